// Round 1
// 327.201 us; speedup vs baseline: 1.0576x; 1.0576x over previous
//
#include <hip/hip_runtime.h>
#include <math.h>

namespace {
constexpr int Bsz = 4;
constexpr int T   = 2048;
constexpr int C   = 1024;
constexpr int H   = 16;
constexpr int HD  = 64;

typedef short bf16x8 __attribute__((ext_vector_type(8)));
typedef float f32x4  __attribute__((ext_vector_type(4)));

#if defined(__has_builtin)
#if __has_builtin(__builtin_amdgcn_global_load_lds)
#define HAVE_GLL 1
typedef __attribute__((address_space(3))) unsigned int lds_u32_t;
typedef __attribute__((address_space(1))) unsigned int g_u32_t;
#define GLL16(gp, lp)                                                        \
  __builtin_amdgcn_global_load_lds((const g_u32_t*)(gp), (lds_u32_t*)(lp),   \
                                   16, 0, 0)
#endif
#endif

__device__ __forceinline__ unsigned short f2bf(float f) {
  unsigned int u = __builtin_bit_cast(unsigned int, f);
  u += 0x7FFFu + ((u >> 16) & 1u);
  return (unsigned short)(u >> 16);
}
__device__ __forceinline__ float bf2f(unsigned short s) {
  unsigned int u = ((unsigned int)s) << 16;
  return __builtin_bit_cast(float, u);
}
// Packed f32->bf16 (RNE), low16 = a, high16 = b. One VOP3 instr vs 3 ops.
__device__ __forceinline__ unsigned int cvtpk_bf16(float a, float b) {
  unsigned int r;
  asm("v_cvt_pk_bf16_f32 %0, %1, %2" : "=v"(r) : "v"(a), "v"(b));
  return r;
}

// ---------------- fp32 -> bf16 (same layout) ----------------
__global__ __launch_bounds__(256) void f32_to_bf16_kernel(
    const float* __restrict__ in, unsigned short* __restrict__ out, int n4) {
  int i = blockIdx.x * 256 + threadIdx.x;
  if (i < n4) {
    float4 v = ((const float4*)in)[i];
    ushort4 o;
    o.x = f2bf(v.x); o.y = f2bf(v.y); o.z = f2bf(v.z); o.w = f2bf(v.w);
    ((ushort4*)out)[i] = o;
  }
}

// ---------------- W [K,N] fp32 -> Wt [N,K] bf16 ----------------
__global__ __launch_bounds__(256) void transpose_bf16_kernel(
    const float* __restrict__ W, unsigned short* __restrict__ Wt, int K, int N) {
  __shared__ float tile[32][33];
  const int n0 = blockIdx.x * 32, k0 = blockIdx.y * 32;
  const int r = threadIdx.x >> 3, c4 = threadIdx.x & 7;
  float4 v = *(const float4*)(W + (size_t)(k0 + r) * N + n0 + c4 * 4);
  tile[r][c4 * 4 + 0] = v.x;
  tile[r][c4 * 4 + 1] = v.y;
  tile[r][c4 * 4 + 2] = v.z;
  tile[r][c4 * 4 + 3] = v.w;
  __syncthreads();
  ushort4 o;
  o.x = f2bf(tile[c4 * 4 + 0][r]);
  o.y = f2bf(tile[c4 * 4 + 1][r]);
  o.z = f2bf(tile[c4 * 4 + 2][r]);
  o.w = f2bf(tile[c4 * 4 + 3][r]);
  *(ushort4*)(Wt + (size_t)(n0 + r) * K + k0 + c4 * 4) = o;
}

// ---------------- bf16 MFMA GEMM: C[M,N] = A[M,K] @ Bt[N,K]^T ----------------
template <int MODE>
__global__ __launch_bounds__(256) void gemm_bt(
    const unsigned short* __restrict__ A, const unsigned short* __restrict__ Bt,
    float* __restrict__ Cout, unsigned short* __restrict__ qp,
    unsigned short* __restrict__ kp, unsigned short* __restrict__ vp,
    int M, int N, int K) {
  __shared__ __align__(16) unsigned short As[128 * 32];
  __shared__ __align__(16) unsigned short Bs[128 * 32];
  const int tid = threadIdx.x;
  const int lane = tid & 63, w = tid >> 6;
  const int wr = w & 1, wc = w >> 1;
  const int l15 = lane & 15, quad = lane >> 4;
  const int m0 = blockIdx.y * 128, n0 = blockIdx.x * 128;

  const int srow = lane >> 2;
  const int schunk = (lane & 3) * 8;
  const unsigned short* gA = A + (size_t)(m0 + w * 32 + srow) * K + schunk;
  const unsigned short* gB = Bt + (size_t)(n0 + w * 32 + srow) * K + schunk;
  unsigned short* lA0 = &As[(w * 32) * 32 + lane * 8];
  unsigned short* lA1 = &As[(w * 32 + 16) * 32 + lane * 8];
  unsigned short* lB0 = &Bs[(w * 32) * 32 + lane * 8];
  unsigned short* lB1 = &Bs[(w * 32 + 16) * 32 + lane * 8];

  f32x4 acc[4][4] = {};

  for (int k0 = 0; k0 < K; k0 += 32) {
    __syncthreads();
#ifdef HAVE_GLL
    GLL16(gA + k0, lA0);
    GLL16(gA + (size_t)16 * K + k0, lA1);
    GLL16(gB + k0, lB0);
    GLL16(gB + (size_t)16 * K + k0, lB1);
#else
    *(uint4*)lA0 = *(const uint4*)(gA + k0);
    *(uint4*)lA1 = *(const uint4*)(gA + (size_t)16 * K + k0);
    *(uint4*)lB0 = *(const uint4*)(gB + k0);
    *(uint4*)lB1 = *(const uint4*)(gB + (size_t)16 * K + k0);
#endif
    __syncthreads();

    bf16x8 af[4], bfr[4];
#pragma unroll
    for (int mf = 0; mf < 4; ++mf)
      af[mf] = *(const bf16x8*)&As[(wr * 64 + mf * 16 + l15) * 32 + quad * 8];
#pragma unroll
    for (int nf = 0; nf < 4; ++nf)
      bfr[nf] = *(const bf16x8*)&Bs[(wc * 64 + nf * 16 + l15) * 32 + quad * 8];
#pragma unroll
    for (int mf = 0; mf < 4; ++mf)
#pragma unroll
      for (int nf = 0; nf < 4; ++nf)
        acc[mf][nf] = __builtin_amdgcn_mfma_f32_16x16x32_bf16(
            af[mf], bfr[nf], acc[mf][nf], 0, 0, 0);
  }

#pragma unroll
  for (int mf = 0; mf < 4; ++mf) {
    const int row0 = m0 + wr * 64 + mf * 16 + quad * 4;
#pragma unroll
    for (int nf = 0; nf < 4; ++nf) {
      if (MODE == 0) {
#pragma unroll
        for (int r = 0; r < 4; ++r) {
          const int col = n0 + wc * 64 + nf * 16 + l15;
          Cout[(size_t)(row0 + r) * N + col] = acc[mf][nf][r];
        }
      } else {
        const int col = n0 + wc * 64 + nf * 16 + l15;
        const int which = col >> 10;
        const int rem = col & (C - 1);
        const int h = rem >> 6, hd = rem & 63;
        const int b = row0 >> 11, t0 = row0 & (T - 1);
        if (which == 2) {
          ushort4 pv;
          pv.x = f2bf(acc[mf][nf][0]);
          pv.y = f2bf(acc[mf][nf][1]);
          pv.z = f2bf(acc[mf][nf][2]);
          pv.w = f2bf(acc[mf][nf][3]);
          *(ushort4*)(vp + (((size_t)(b * H + h)) * HD + hd) * T + t0) = pv;
        } else {
          unsigned short* dst = which == 0 ? qp : kp;
#pragma unroll
          for (int r = 0; r < 4; ++r)
            dst[(((size_t)(b * H + h)) * T + t0 + r) * HD + hd] =
                f2bf(acc[mf][nf][r]);
        }
      }
    }
  }
}

// ---------------- RoPE in place on bf16 q,k [B,H,T,HD] ----------------
// q additionally pre-scaled by 0.125*log2(e): softmax scale folded into Q so
// the attention kernel's QK^T output is already in the exp2 domain.
__global__ __launch_bounds__(256) void rope_bf16(unsigned short* __restrict__ q,
                                                 unsigned short* __restrict__ k,
                                                 const int* __restrict__ idx) {
  const size_t g = (size_t)blockIdx.x * 8 + (threadIdx.x >> 5);
  const int lane = threadIdx.x & 31;
  const int t = (int)(g & (size_t)(T - 1));
  const int bh = (int)(g >> 11);
  const int b = bh >> 4;
  const int pos = idx[b * T + t];
  const float inv = 1.0f / powf(10000.0f, (float)lane * (1.0f / 32.0f));
  float sn, cs;
  sincosf((float)pos * inv, &sn, &cs);
  const float SC = 0.18033688f;  // 0.125 * log2(e)
  const float snq = sn * SC, csq = cs * SC;
  const size_t base = g * (size_t)HD;
  float x1 = bf2f(q[base + lane]), x2 = bf2f(q[base + 32 + lane]);
  q[base + lane]      = f2bf(x1 * csq - x2 * snq);
  q[base + 32 + lane] = f2bf(x1 * snq + x2 * csq);
  x1 = bf2f(k[base + lane]);
  x2 = bf2f(k[base + 32 + lane]);
  k[base + lane]      = f2bf(x1 * cs - x2 * sn);
  k[base + 32 + lane] = f2bf(x1 * sn + x2 * cs);
}

// ---------------- MFMA flash attention ----------------
// Mirror-pair balance: block bx handles q-tiles {bx, 31-bx} (64 rows each)
// -> every block runs exactly 33 k-iterations. 4 waves each own 16 q-rows.
// K/V double-buffered in LDS; ONE barrier per iteration. S^T/O^T formulation
// keeps the softmax row in the lane dimension.
// VALU-debloat (this round):
//  - Q pre-scaled in rope -> no per-score scale mul.
//  - mask applied only when a per-k-tile idx max exceeds the wave's q-pos min
//    (general; with monotone indices only the diagonal tile masks).
//  - defer-max rescale (THR=8): O/l rescale skipped unless some row's max
//    grew past m_run+8 (P bounded by 2^8; f32 accum absorbs it).
//  - v_cvt_pk_bf16_f32 for P->bf16 (1 instr/pair, RNE).
// XCD remap: the 16 q-blocks of one (b,h) land on one XCD so K/V (512 KB)
// stays L2-resident (8 heads/XCD = 4 MB working set).
__global__ __launch_bounds__(256) void flash_attn_mfma(
    const unsigned short* __restrict__ q, const unsigned short* __restrict__ k,
    const unsigned short* __restrict__ vt, const int* __restrict__ idx,
    unsigned short* __restrict__ y) {
  __shared__ __align__(16) unsigned short Ks[2][64][72];   // [buf][key][d]
  __shared__ __align__(16) unsigned short Vts[2][64][72];  // [buf][d][key]
  __shared__ __align__(16) unsigned short Pq[64][72];      // [qrow][key]
  __shared__ int kmaxs[32];                                // per-k-tile idx max

  const int tid = threadIdx.x;
  const int lane = tid & 63, w = tid >> 6;
  const int l15 = lane & 15, quad = lane >> 4;

  // XCD-aware bijective remap (1024 blocks, 1024 % 8 == 0).
  const int flat = (blockIdx.z * H + blockIdx.y) * 16 + blockIdx.x;
  const int slot = flat >> 3;
  const int bh_i = (flat & 7) * 8 + (slot >> 4);  // 0..63 = b*H+h
  const int bx = slot & 15;
  const int h = bh_i & (H - 1), b = bh_i >> 4;

  const size_t bh = (size_t)bh_i;
  const unsigned short* qg = q + bh * T * HD;
  const unsigned short* kg = k + bh * T * HD;
  const unsigned short* vg = vt + bh * HD * T;
  const int* idxb = idx + b * T;

  // per-64-key-tile idx maxima (one-time; visible after prologue barrier)
  if (tid < 32) {
    const int4* p4 = (const int4*)(idxb + (tid << 6));
    int m = p4[0].x;
#pragma unroll
    for (int j = 0; j < 16; ++j) {
      int4 v = p4[j];
      m = max(m, max(max(v.x, v.y), max(v.z, v.w)));
    }
    kmaxs[tid] = m;
  }

  // staging coords: 64 rows x 8 chunks(16B) = 512 -> 2 per thread
  const int r1 = tid >> 3, c1 = tid & 7;
  const int r2 = r1 + 32;

  for (int ti = 0; ti < 2; ++ti) {
    const int qt = (ti == 0) ? bx : 31 - bx;
    const int q0 = qt * 64;
    const int qrow = q0 + w * 16 + l15;  // this lane's q row

    const bf16x8 bq0 = *(const bf16x8*)(qg + (size_t)qrow * HD + quad * 8);
    const bf16x8 bq1 = *(const bf16x8*)(qg + (size_t)qrow * HD + 32 + quad * 8);
    const int pq = idxb[qrow];
    // wave-wide min of q positions (pq depends only on l15)
    int mq = pq;
    mq = min(mq, __shfl_xor(mq, 1));
    mq = min(mq, __shfl_xor(mq, 2));
    mq = min(mq, __shfl_xor(mq, 4));
    mq = min(mq, __shfl_xor(mq, 8));

    float m_run = -1e38f, l_run = 0.0f;
    f32x4 Oa[4] = {};

    // prologue: stage kt=0 into buf 0
    {
      uint4 ka = *(const uint4*)(kg + (size_t)r1 * HD + c1 * 8);
      uint4 kb = *(const uint4*)(kg + (size_t)r2 * HD + c1 * 8);
      uint4 va = *(const uint4*)(vg + (size_t)r1 * T + c1 * 8);
      uint4 vb = *(const uint4*)(vg + (size_t)r2 * T + c1 * 8);
      __syncthreads();  // all waves done with previous tile's buffers
      *(uint4*)&Ks[0][r1][c1 * 8] = ka;
      *(uint4*)&Ks[0][r2][c1 * 8] = kb;
      *(uint4*)&Vts[0][r1][c1 * 8] = va;
      *(uint4*)&Vts[0][r2][c1 * 8] = vb;
    }

    for (int kt = 0; kt <= qt; ++kt) {
      const int cur = kt & 1;
      const int k0 = kt * 64;
      __syncthreads();  // stage(kt) visible; buf[cur^1] free for restaging

      // issue global loads for kt+1 now; consumed at iteration end
      uint4 nka, nkb, nva, nvb;
      if (kt < qt) {
        const int kn = k0 + 64;
        nka = *(const uint4*)(kg + (size_t)(kn + r1) * HD + c1 * 8);
        nkb = *(const uint4*)(kg + (size_t)(kn + r2) * HD + c1 * 8);
        nva = *(const uint4*)(vg + (size_t)r1 * T + kn + c1 * 8);
        nvb = *(const uint4*)(vg + (size_t)r2 * T + kn + c1 * 8);
      }

      // S^T = K·Q^T : lane = qrow, reg r of tile nf = key nf*16+quad*4+r
      // (Q pre-scaled -> Sa is already in the exp2 domain)
      f32x4 Sa[4];
#pragma unroll
      for (int nf = 0; nf < 4; ++nf) {
        bf16x8 ak0 = *(const bf16x8*)&Ks[cur][nf * 16 + l15][quad * 8];
        bf16x8 ak1 = *(const bf16x8*)&Ks[cur][nf * 16 + l15][32 + quad * 8];
        f32x4 s = {};
        s = __builtin_amdgcn_mfma_f32_16x16x32_bf16(ak0, bq0, s, 0, 0, 0);
        s = __builtin_amdgcn_mfma_f32_16x16x32_bf16(ak1, bq1, s, 0, 0, 0);
        Sa[nf] = s;
      }

      // causal mask only if this k-tile can exceed some q position (uniform)
      if (kmaxs[kt] > mq) {
#pragma unroll
        for (int nf = 0; nf < 4; ++nf) {
          const int4 pk4 = *(const int4*)(idxb + k0 + nf * 16 + quad * 4);
          if (pk4.x > pq) Sa[nf][0] = -3e38f;
          if (pk4.y > pq) Sa[nf][1] = -3e38f;
          if (pk4.z > pq) Sa[nf][2] = -3e38f;
          if (pk4.w > pq) Sa[nf][3] = -3e38f;
        }
      }

      // row max (row lives in lane -> 2 shfls)
      float m0 = fmaxf(fmaxf(Sa[0][0], Sa[0][1]), fmaxf(Sa[0][2], Sa[0][3]));
      float m1 = fmaxf(fmaxf(Sa[1][0], Sa[1][1]), fmaxf(Sa[1][2], Sa[1][3]));
      float m2 = fmaxf(fmaxf(Sa[2][0], Sa[2][1]), fmaxf(Sa[2][2], Sa[2][3]));
      float m3 = fmaxf(fmaxf(Sa[3][0], Sa[3][1]), fmaxf(Sa[3][2], Sa[3][3]));
      float mx = fmaxf(fmaxf(m0, m1), fmaxf(m2, m3));
      mx = fmaxf(mx, __shfl_xor(mx, 16));
      mx = fmaxf(mx, __shfl_xor(mx, 32));

      // defer-max: rescale only when some row grew past m_run+8
      if (!__all(mx <= m_run + 8.0f)) {
        const float mn = fmaxf(m_run, mx);
        const float alpha = exp2f(m_run - mn);
        m_run = mn;
        l_run *= alpha;
#pragma unroll
        for (int nfd = 0; nfd < 4; ++nfd)
#pragma unroll
          for (int r = 0; r < 4; ++r) Oa[nfd][r] *= alpha;
      }

      // P = exp2(S - m_run); 4-way partial sums for ILP
      float s0 = 0.f, s1 = 0.f, s2 = 0.f, s3 = 0.f;
#pragma unroll
      for (int nf = 0; nf < 4; ++nf) {
        float p0 = exp2f(Sa[nf][0] - m_run);
        float p1 = exp2f(Sa[nf][1] - m_run);
        float p2 = exp2f(Sa[nf][2] - m_run);
        float p3 = exp2f(Sa[nf][3] - m_run);
        Sa[nf][0] = p0; Sa[nf][1] = p1; Sa[nf][2] = p2; Sa[nf][3] = p3;
        s0 += p0; s1 += p1; s2 += p2; s3 += p3;
      }
      float sum = (s0 + s1) + (s2 + s3);
      sum += __shfl_xor(sum, 16);
      sum += __shfl_xor(sum, 32);
      l_run += sum;

      // P -> LDS (wave-private rows), packed RNE bf16
#pragma unroll
      for (int nf = 0; nf < 4; ++nf) {
        uint2 pw;
        pw.x = cvtpk_bf16(Sa[nf][0], Sa[nf][1]);
        pw.y = cvtpk_bf16(Sa[nf][2], Sa[nf][3]);
        *(uint2*)&Pq[w * 16 + l15][nf * 16 + quad * 4] = pw;
      }

      asm volatile("s_waitcnt lgkmcnt(0)" ::: "memory");

      const bf16x8 bp0 = *(const bf16x8*)&Pq[w * 16 + l15][quad * 8];
      const bf16x8 bp1 = *(const bf16x8*)&Pq[w * 16 + l15][32 + quad * 8];

      // O^T += V^T · P^T
#pragma unroll
      for (int nfd = 0; nfd < 4; ++nfd) {
        bf16x8 av0 = *(const bf16x8*)&Vts[cur][nfd * 16 + l15][quad * 8];
        bf16x8 av1 = *(const bf16x8*)&Vts[cur][nfd * 16 + l15][32 + quad * 8];
        Oa[nfd] = __builtin_amdgcn_mfma_f32_16x16x32_bf16(av0, bp0, Oa[nfd], 0, 0, 0);
        Oa[nfd] = __builtin_amdgcn_mfma_f32_16x16x32_bf16(av1, bp1, Oa[nfd], 0, 0, 0);
      }

      // write next tile into the spare buffer (waits its loads via dep)
      if (kt < qt) {
        const int nxt = cur ^ 1;
        *(uint4*)&Ks[nxt][r1][c1 * 8] = nka;
        *(uint4*)&Ks[nxt][r2][c1 * 8] = nkb;
        *(uint4*)&Vts[nxt][r1][c1 * 8] = nva;
        *(uint4*)&Vts[nxt][r2][c1 * 8] = nvb;
      }
    }

    // epilogue: lane = qrow, (quad,reg) = d -> b64 stores
    const float rl = 1.0f / l_run;
    const size_t base = ((size_t)b * T + qrow) * (size_t)C + h * HD;
#pragma unroll
    for (int nfd = 0; nfd < 4; ++nfd) {
      ushort4 o;
      o.x = f2bf(Oa[nfd][0] * rl);
      o.y = f2bf(Oa[nfd][1] * rl);
      o.z = f2bf(Oa[nfd][2] * rl);
      o.w = f2bf(Oa[nfd][3] * rl);
      *(ushort4*)(y + base + nfd * 16 + quad * 4) = o;
    }
  }
}

}  // namespace

extern "C" void kernel_launch(void* const* d_in, const int* in_sizes, int n_in,
                              void* d_out, int out_size, void* d_ws,
                              size_t ws_size, hipStream_t stream) {
  const float* x      = (const float*)d_in[0];
  const float* W_attn = (const float*)d_in[1];
  const float* W_proj = (const float*)d_in[2];
  const int* indices  = (const int*)d_in[3];
  float* out = (float*)d_out;

  const size_t nM = (size_t)Bsz * T * C;
  unsigned short* xb  = (unsigned short*)d_ws;
  unsigned short* wat = xb + nM;
  unsigned short* wpt = wat + (size_t)3 * C * C;
  unsigned short* qp  = wpt + (size_t)C * C;           // [B,H,T,HD]
  unsigned short* kp  = qp + nM;                       // [B,H,T,HD]
  unsigned short* vp  = kp + nM;                       // [B,H,HD,T]
  unsigned short* yb  = vp + nM;                       // [B,T,C]

  f32_to_bf16_kernel<<<(int)(nM / 4 / 256), 256, 0, stream>>>(x, xb, (int)(nM / 4));
  transpose_bf16_kernel<<<dim3(3 * C / 32, C / 32), 256, 0, stream>>>(W_attn, wat, C, 3 * C);
  transpose_bf16_kernel<<<dim3(C / 32, C / 32), 256, 0, stream>>>(W_proj, wpt, C, C);
  gemm_bt<1><<<dim3(3 * C / 128, Bsz * T / 128), 256, 0, stream>>>(
      xb, wat, nullptr, qp, kp, vp, Bsz * T, 3 * C, C);
  rope_bf16<<<(Bsz * H * T) / 8, 256, 0, stream>>>(qp, kp, indices);
  flash_attn_mfma<<<dim3(16, H, Bsz), 256, 0, stream>>>(qp, kp, vp, indices, yb);
  gemm_bt<0><<<dim3(C / 128, Bsz * T / 128), 256, 0, stream>>>(
      yb, wpt, out, nullptr, nullptr, nullptr, Bsz * T, C, C);
}

// Round 2
// 313.033 us; speedup vs baseline: 1.1055x; 1.0453x over previous
//
#include <hip/hip_runtime.h>
#include <math.h>

namespace {
constexpr int Bsz = 4;
constexpr int T   = 2048;
constexpr int C   = 1024;
constexpr int H   = 16;
constexpr int HD  = 64;

typedef short bf16x8 __attribute__((ext_vector_type(8)));
typedef float f32x4  __attribute__((ext_vector_type(4)));

#if defined(__has_builtin)
#if __has_builtin(__builtin_amdgcn_global_load_lds)
#define HAVE_GLL 1
typedef __attribute__((address_space(3))) unsigned int lds_u32_t;
typedef __attribute__((address_space(1))) unsigned int g_u32_t;
#define GLL16(gp, lp)                                                        \
  __builtin_amdgcn_global_load_lds((const g_u32_t*)(gp), (lds_u32_t*)(lp),   \
                                   16, 0, 0)
#endif
#endif

__device__ __forceinline__ unsigned short f2bf(float f) {
  unsigned int u = __builtin_bit_cast(unsigned int, f);
  u += 0x7FFFu + ((u >> 16) & 1u);
  return (unsigned short)(u >> 16);
}
__device__ __forceinline__ float bf2f(unsigned short s) {
  unsigned int u = ((unsigned int)s) << 16;
  return __builtin_bit_cast(float, u);
}
// Packed f32->bf16 (RNE), low16 = a, high16 = b. One VOP3 instr vs 3 ops.
__device__ __forceinline__ unsigned int cvtpk_bf16(float a, float b) {
  unsigned int r;
  asm("v_cvt_pk_bf16_f32 %0, %1, %2" : "=v"(r) : "v"(a), "v"(b));
  return r;
}

// ---------------- fp32 -> bf16 (same layout) ----------------
__global__ __launch_bounds__(256) void f32_to_bf16_kernel(
    const float* __restrict__ in, unsigned short* __restrict__ out, int n4) {
  int i = blockIdx.x * 256 + threadIdx.x;
  if (i < n4) {
    float4 v = ((const float4*)in)[i];
    ushort4 o;
    o.x = f2bf(v.x); o.y = f2bf(v.y); o.z = f2bf(v.z); o.w = f2bf(v.w);
    ((ushort4*)out)[i] = o;
  }
}

// ---------------- W [K,N] fp32 -> Wt [N,K] bf16 ----------------
__global__ __launch_bounds__(256) void transpose_bf16_kernel(
    const float* __restrict__ W, unsigned short* __restrict__ Wt, int K, int N) {
  __shared__ float tile[32][33];
  const int n0 = blockIdx.x * 32, k0 = blockIdx.y * 32;
  const int r = threadIdx.x >> 3, c4 = threadIdx.x & 7;
  float4 v = *(const float4*)(W + (size_t)(k0 + r) * N + n0 + c4 * 4);
  tile[r][c4 * 4 + 0] = v.x;
  tile[r][c4 * 4 + 1] = v.y;
  tile[r][c4 * 4 + 2] = v.z;
  tile[r][c4 * 4 + 3] = v.w;
  __syncthreads();
  ushort4 o;
  o.x = f2bf(tile[c4 * 4 + 0][r]);
  o.y = f2bf(tile[c4 * 4 + 1][r]);
  o.z = f2bf(tile[c4 * 4 + 2][r]);
  o.w = f2bf(tile[c4 * 4 + 3][r]);
  *(ushort4*)(Wt + (size_t)(n0 + r) * K + k0 + c4 * 4) = o;
}

// ---------------- bf16 MFMA GEMM: C[M,N] = A[M,K] @ Bt[N,K]^T ----------------
template <int MODE>
__global__ __launch_bounds__(256) void gemm_bt(
    const unsigned short* __restrict__ A, const unsigned short* __restrict__ Bt,
    float* __restrict__ Cout, unsigned short* __restrict__ qp,
    unsigned short* __restrict__ kp, unsigned short* __restrict__ vp,
    int M, int N, int K) {
  __shared__ __align__(16) unsigned short As[128 * 32];
  __shared__ __align__(16) unsigned short Bs[128 * 32];
  const int tid = threadIdx.x;
  const int lane = tid & 63, w = tid >> 6;
  const int wr = w & 1, wc = w >> 1;
  const int l15 = lane & 15, quad = lane >> 4;
  const int m0 = blockIdx.y * 128, n0 = blockIdx.x * 128;

  const int srow = lane >> 2;
  const int schunk = (lane & 3) * 8;
  const unsigned short* gA = A + (size_t)(m0 + w * 32 + srow) * K + schunk;
  const unsigned short* gB = Bt + (size_t)(n0 + w * 32 + srow) * K + schunk;
  unsigned short* lA0 = &As[(w * 32) * 32 + lane * 8];
  unsigned short* lA1 = &As[(w * 32 + 16) * 32 + lane * 8];
  unsigned short* lB0 = &Bs[(w * 32) * 32 + lane * 8];
  unsigned short* lB1 = &Bs[(w * 32 + 16) * 32 + lane * 8];

  f32x4 acc[4][4] = {};

  for (int k0 = 0; k0 < K; k0 += 32) {
    __syncthreads();
#ifdef HAVE_GLL
    GLL16(gA + k0, lA0);
    GLL16(gA + (size_t)16 * K + k0, lA1);
    GLL16(gB + k0, lB0);
    GLL16(gB + (size_t)16 * K + k0, lB1);
#else
    *(uint4*)lA0 = *(const uint4*)(gA + k0);
    *(uint4*)lA1 = *(const uint4*)(gA + (size_t)16 * K + k0);
    *(uint4*)lB0 = *(const uint4*)(gB + k0);
    *(uint4*)lB1 = *(const uint4*)(gB + (size_t)16 * K + k0);
#endif
    __syncthreads();

    bf16x8 af[4], bfr[4];
#pragma unroll
    for (int mf = 0; mf < 4; ++mf)
      af[mf] = *(const bf16x8*)&As[(wr * 64 + mf * 16 + l15) * 32 + quad * 8];
#pragma unroll
    for (int nf = 0; nf < 4; ++nf)
      bfr[nf] = *(const bf16x8*)&Bs[(wc * 64 + nf * 16 + l15) * 32 + quad * 8];
#pragma unroll
    for (int mf = 0; mf < 4; ++mf)
#pragma unroll
      for (int nf = 0; nf < 4; ++nf)
        acc[mf][nf] = __builtin_amdgcn_mfma_f32_16x16x32_bf16(
            af[mf], bfr[nf], acc[mf][nf], 0, 0, 0);
  }

#pragma unroll
  for (int mf = 0; mf < 4; ++mf) {
    const int row0 = m0 + wr * 64 + mf * 16 + quad * 4;
#pragma unroll
    for (int nf = 0; nf < 4; ++nf) {
      if (MODE == 0) {
#pragma unroll
        for (int r = 0; r < 4; ++r) {
          const int col = n0 + wc * 64 + nf * 16 + l15;
          Cout[(size_t)(row0 + r) * N + col] = acc[mf][nf][r];
        }
      } else {
        const int col = n0 + wc * 64 + nf * 16 + l15;
        const int which = col >> 10;
        const int rem = col & (C - 1);
        const int h = rem >> 6, hd = rem & 63;
        const int b = row0 >> 11, t0 = row0 & (T - 1);
        if (which == 2) {
          ushort4 pv;
          pv.x = f2bf(acc[mf][nf][0]);
          pv.y = f2bf(acc[mf][nf][1]);
          pv.z = f2bf(acc[mf][nf][2]);
          pv.w = f2bf(acc[mf][nf][3]);
          *(ushort4*)(vp + (((size_t)(b * H + h)) * HD + hd) * T + t0) = pv;
        } else {
          unsigned short* dst = which == 0 ? qp : kp;
#pragma unroll
          for (int r = 0; r < 4; ++r)
            dst[(((size_t)(b * H + h)) * T + t0 + r) * HD + hd] =
                f2bf(acc[mf][nf][r]);
        }
      }
    }
  }
}

// ---------------- RoPE in place on bf16 q,k [B,H,T,HD] ----------------
// One 32-lane group owns one (b,t): trig computed ONCE (exp2f for the inverse
// frequency instead of powf) and reused across all 16 heads. q additionally
// pre-scaled by 0.125*log2(e) so flash's QK^T lands in the exp2 domain.
__global__ __launch_bounds__(256) void rope_bf16(unsigned short* __restrict__ q,
                                                 unsigned short* __restrict__ k,
                                                 const int* __restrict__ idx) {
  const int g = blockIdx.x * 8 + (threadIdx.x >> 5);  // (b,t) flat index
  const int lane = threadIdx.x & 31;
  const int b = g >> 11, t = g & (T - 1);
  const int pos = idx[b * T + t];
  // inv = 10000^(-lane/32) = exp2(-lane * log2(10000)/32)
  const float inv = exp2f((float)lane * -0.41524101186f);
  float sn, cs;
  sincosf((float)pos * inv, &sn, &cs);
  const float SC = 0.18033688f;  // 0.125 * log2(e)
  const float snq = sn * SC, csq = cs * SC;
  const size_t base0 = ((size_t)b * H * T + t) * HD + lane;
#pragma unroll 4
  for (int h = 0; h < H; ++h) {
    const size_t base = base0 + (size_t)h * T * HD;
    float x1 = bf2f(q[base]), x2 = bf2f(q[base + 32]);
    q[base]      = f2bf(x1 * csq - x2 * snq);
    q[base + 32] = f2bf(x1 * snq + x2 * csq);
    x1 = bf2f(k[base]);
    x2 = bf2f(k[base + 32]);
    k[base]      = f2bf(x1 * cs - x2 * sn);
    k[base + 32] = f2bf(x1 * sn + x2 * cs);
  }
}

// ---------------- MFMA flash attention ----------------
// Mirror-pair balance: block bx handles q-tiles {bx, 31-bx} (64 rows each)
// -> every block runs exactly 33 k-iterations. 4 waves each own 16 q-rows.
// K/V double-buffered in LDS; ONE barrier per iteration. S^T/O^T formulation
// keeps the softmax row in the lane dimension.
// This round: LDS diet for occupancy. Pads dropped; XOR swizzle
// (short_col ^= (row&7)<<3, the T2 recipe at 16B granularity) keeps the same
// bank distribution as the old +8 pad. kmax table moved from LDS to per-lane
// registers (one __shfl per iter). LDS = 40960 B exactly -> 4 blocks/CU
// (was 46592 -> 3). s_setprio(1) wraps both MFMA clusters (T5, +4-7% attn).
__global__ __launch_bounds__(256) void flash_attn_mfma(
    const unsigned short* __restrict__ q, const unsigned short* __restrict__ k,
    const unsigned short* __restrict__ vt, const int* __restrict__ idx,
    unsigned short* __restrict__ y) {
  __shared__ __align__(16) unsigned short Ks[2][64 * 64];   // [buf][key][d] swz
  __shared__ __align__(16) unsigned short Vts[2][64 * 64];  // [buf][d][key] swz
  __shared__ __align__(16) unsigned short Pq[64 * 64];      // [qrow][key] swz

  const int tid = threadIdx.x;
  const int lane = tid & 63, w = tid >> 6;
  const int l15 = lane & 15, quad = lane >> 4;

  // XCD-aware bijective remap (1024 blocks, 1024 % 8 == 0): all 16 q-blocks
  // of one (b,h) land on one XCD -> K/V stays L2-resident.
  const int flat = (blockIdx.z * H + blockIdx.y) * 16 + blockIdx.x;
  const int slot = flat >> 3;
  const int bh_i = (flat & 7) * 8 + (slot >> 4);  // 0..63 = b*H+h
  const int bx = slot & 15;
  const int h = bh_i & (H - 1), b = bh_i >> 4;

  const size_t bh = (size_t)bh_i;
  const unsigned short* qg = q + bh * T * HD;
  const unsigned short* kg = k + bh * T * HD;
  const unsigned short* vg = vt + bh * HD * T;
  const int* idxb = idx + b * T;

  // per-64-key-tile idx maxima, held in registers: lane i maxes
  // idx[i*32, i*32+32); after the xor-1 combine, lanes {2j,2j+1} hold the
  // max of tile j. Retrieved per-iter with one __shfl.
  int km;
  {
    const int4* p4 = (const int4*)(idxb + (lane << 5));
    int4 v0 = p4[0];
    int m = max(max(v0.x, v0.y), max(v0.z, v0.w));
#pragma unroll
    for (int j = 1; j < 8; ++j) {
      int4 v = p4[j];
      m = max(m, max(max(v.x, v.y), max(v.z, v.w)));
    }
    km = max(m, __shfl_xor(m, 1));
  }

  // staging coords: 64 rows x 8 chunks(16B) = 512 -> 2 per thread
  const int r1 = tid >> 3, c1 = tid & 7;
  const int r2 = r1 + 32;
  // swizzled short-offsets (row*64 + (col ^ ((row&7)<<3))); r2&7 == r1&7
  const int swS1 = r1 * 64 + ((c1 * 8) ^ ((r1 & 7) << 3));
  const int swS2 = r2 * 64 + ((c1 * 8) ^ ((r1 & 7) << 3));
  // read-side XOR term for this lane (rows read are nf*16+l15 -> low3 = l15&7)
  const int rx = (l15 & 7) << 3;

  for (int ti = 0; ti < 2; ++ti) {
    const int qt = (ti == 0) ? bx : 31 - bx;
    const int q0 = qt * 64;
    const int qrow = q0 + w * 16 + l15;  // this lane's q row

    const bf16x8 bq0 = *(const bf16x8*)(qg + (size_t)qrow * HD + quad * 8);
    const bf16x8 bq1 = *(const bf16x8*)(qg + (size_t)qrow * HD + 32 + quad * 8);
    const int pq = idxb[qrow];
    // wave-wide min of q positions (pq depends only on l15)
    int mq = pq;
    mq = min(mq, __shfl_xor(mq, 1));
    mq = min(mq, __shfl_xor(mq, 2));
    mq = min(mq, __shfl_xor(mq, 4));
    mq = min(mq, __shfl_xor(mq, 8));

    float m_run = -1e38f, l_run = 0.0f;
    f32x4 Oa[4] = {};

    // prologue: stage kt=0 into buf 0
    {
      uint4 ka = *(const uint4*)(kg + (size_t)r1 * HD + c1 * 8);
      uint4 kb = *(const uint4*)(kg + (size_t)r2 * HD + c1 * 8);
      uint4 va = *(const uint4*)(vg + (size_t)r1 * T + c1 * 8);
      uint4 vb = *(const uint4*)(vg + (size_t)r2 * T + c1 * 8);
      __syncthreads();  // all waves done with previous tile's buffers
      *(uint4*)&Ks[0][swS1] = ka;
      *(uint4*)&Ks[0][swS2] = kb;
      *(uint4*)&Vts[0][swS1] = va;
      *(uint4*)&Vts[0][swS2] = vb;
    }

    for (int kt = 0; kt <= qt; ++kt) {
      const int cur = kt & 1;
      const int k0 = kt * 64;
      __syncthreads();  // stage(kt) visible; buf[cur^1] free for restaging

      // issue global loads for kt+1 now; consumed at iteration end
      uint4 nka, nkb, nva, nvb;
      if (kt < qt) {
        const int kn = k0 + 64;
        nka = *(const uint4*)(kg + (size_t)(kn + r1) * HD + c1 * 8);
        nkb = *(const uint4*)(kg + (size_t)(kn + r2) * HD + c1 * 8);
        nva = *(const uint4*)(vg + (size_t)r1 * T + kn + c1 * 8);
        nvb = *(const uint4*)(vg + (size_t)r2 * T + kn + c1 * 8);
      }

      // S^T = K·Q^T : lane = qrow, reg r of tile nf = key nf*16+quad*4+r
      // (Q pre-scaled -> Sa is already in the exp2 domain)
      f32x4 Sa[4];
      __builtin_amdgcn_s_setprio(1);
#pragma unroll
      for (int nf = 0; nf < 4; ++nf) {
        const int row = (nf * 16 + l15) * 64;
        bf16x8 ak0 = *(const bf16x8*)&Ks[cur][row + ((quad * 8) ^ rx)];
        bf16x8 ak1 = *(const bf16x8*)&Ks[cur][row + ((32 + quad * 8) ^ rx)];
        f32x4 s = {};
        s = __builtin_amdgcn_mfma_f32_16x16x32_bf16(ak0, bq0, s, 0, 0, 0);
        s = __builtin_amdgcn_mfma_f32_16x16x32_bf16(ak1, bq1, s, 0, 0, 0);
        Sa[nf] = s;
      }
      __builtin_amdgcn_s_setprio(0);

      // causal mask only if this k-tile can exceed some q position (uniform)
      const int kmt = __shfl(km, kt << 1);
      if (kmt > mq) {
#pragma unroll
        for (int nf = 0; nf < 4; ++nf) {
          const int4 pk4 = *(const int4*)(idxb + k0 + nf * 16 + quad * 4);
          if (pk4.x > pq) Sa[nf][0] = -3e38f;
          if (pk4.y > pq) Sa[nf][1] = -3e38f;
          if (pk4.z > pq) Sa[nf][2] = -3e38f;
          if (pk4.w > pq) Sa[nf][3] = -3e38f;
        }
      }

      // row max via max3 (row lives in lane -> 2 shfls)
      float mx = fmaxf(
          fmaxf(fmaxf(fmaxf(Sa[0][0], Sa[0][1]), Sa[0][2]),
                fmaxf(fmaxf(Sa[0][3], Sa[1][0]), Sa[1][1])),
          fmaxf(fmaxf(fmaxf(Sa[1][2], Sa[1][3]), Sa[2][0]),
                fmaxf(fmaxf(Sa[2][1], Sa[2][2]), Sa[2][3])));
      mx = fmaxf(mx, fmaxf(fmaxf(Sa[3][0], Sa[3][1]), fmaxf(Sa[3][2], Sa[3][3])));
      mx = fmaxf(mx, __shfl_xor(mx, 16));
      mx = fmaxf(mx, __shfl_xor(mx, 32));

      // defer-max: rescale only when some row grew past m_run+8
      if (!__all(mx <= m_run + 8.0f)) {
        const float mn = fmaxf(m_run, mx);
        const float alpha = exp2f(m_run - mn);
        m_run = mn;
        l_run *= alpha;
#pragma unroll
        for (int nfd = 0; nfd < 4; ++nfd)
#pragma unroll
          for (int r = 0; r < 4; ++r) Oa[nfd][r] *= alpha;
      }

      // P = exp2(S - m_run); 4-way partial sums for ILP
      float s0 = 0.f, s1 = 0.f, s2 = 0.f, s3 = 0.f;
#pragma unroll
      for (int nf = 0; nf < 4; ++nf) {
        float p0 = exp2f(Sa[nf][0] - m_run);
        float p1 = exp2f(Sa[nf][1] - m_run);
        float p2 = exp2f(Sa[nf][2] - m_run);
        float p3 = exp2f(Sa[nf][3] - m_run);
        Sa[nf][0] = p0; Sa[nf][1] = p1; Sa[nf][2] = p2; Sa[nf][3] = p3;
        s0 += p0; s1 += p1; s2 += p2; s3 += p3;
      }
      float sum = (s0 + s1) + (s2 + s3);
      sum += __shfl_xor(sum, 16);
      sum += __shfl_xor(sum, 32);
      l_run += sum;

      // P -> LDS (wave-private rows), packed RNE bf16, swizzled
      {
        const int prow = (w * 16 + l15) * 64;
#pragma unroll
        for (int nf = 0; nf < 4; ++nf) {
          uint2 pw;
          pw.x = cvtpk_bf16(Sa[nf][0], Sa[nf][1]);
          pw.y = cvtpk_bf16(Sa[nf][2], Sa[nf][3]);
          *(uint2*)&Pq[prow + ((nf * 16 + quad * 4) ^ rx)] = pw;
        }
      }

      asm volatile("s_waitcnt lgkmcnt(0)" ::: "memory");

      const int prow = (w * 16 + l15) * 64;
      const bf16x8 bp0 = *(const bf16x8*)&Pq[prow + ((quad * 8) ^ rx)];
      const bf16x8 bp1 = *(const bf16x8*)&Pq[prow + ((32 + quad * 8) ^ rx)];

      // O^T += V^T · P^T
      __builtin_amdgcn_s_setprio(1);
#pragma unroll
      for (int nfd = 0; nfd < 4; ++nfd) {
        const int vrow = (nfd * 16 + l15) * 64;
        bf16x8 av0 = *(const bf16x8*)&Vts[cur][vrow + ((quad * 8) ^ rx)];
        bf16x8 av1 = *(const bf16x8*)&Vts[cur][vrow + ((32 + quad * 8) ^ rx)];
        Oa[nfd] = __builtin_amdgcn_mfma_f32_16x16x32_bf16(av0, bp0, Oa[nfd], 0, 0, 0);
        Oa[nfd] = __builtin_amdgcn_mfma_f32_16x16x32_bf16(av1, bp1, Oa[nfd], 0, 0, 0);
      }
      __builtin_amdgcn_s_setprio(0);

      // write next tile into the spare buffer (waits its loads via dep)
      if (kt < qt) {
        const int nxt = cur ^ 1;
        *(uint4*)&Ks[nxt][swS1] = nka;
        *(uint4*)&Ks[nxt][swS2] = nkb;
        *(uint4*)&Vts[nxt][swS1] = nva;
        *(uint4*)&Vts[nxt][swS2] = nvb;
      }
    }

    // epilogue: lane = qrow, (quad,reg) = d -> b64 stores
    const float rl = 1.0f / l_run;
    const size_t base = ((size_t)b * T + qrow) * (size_t)C + h * HD;
#pragma unroll
    for (int nfd = 0; nfd < 4; ++nfd) {
      ushort4 o;
      o.x = f2bf(Oa[nfd][0] * rl);
      o.y = f2bf(Oa[nfd][1] * rl);
      o.z = f2bf(Oa[nfd][2] * rl);
      o.w = f2bf(Oa[nfd][3] * rl);
      *(ushort4*)(y + base + nfd * 16 + quad * 4) = o;
    }
  }
}

}  // namespace

extern "C" void kernel_launch(void* const* d_in, const int* in_sizes, int n_in,
                              void* d_out, int out_size, void* d_ws,
                              size_t ws_size, hipStream_t stream) {
  const float* x      = (const float*)d_in[0];
  const float* W_attn = (const float*)d_in[1];
  const float* W_proj = (const float*)d_in[2];
  const int* indices  = (const int*)d_in[3];
  float* out = (float*)d_out;

  const size_t nM = (size_t)Bsz * T * C;
  unsigned short* xb  = (unsigned short*)d_ws;
  unsigned short* wat = xb + nM;
  unsigned short* wpt = wat + (size_t)3 * C * C;
  unsigned short* qp  = wpt + (size_t)C * C;           // [B,H,T,HD]
  unsigned short* kp  = qp + nM;                       // [B,H,T,HD]
  unsigned short* vp  = kp + nM;                       // [B,H,HD,T]
  unsigned short* yb  = vp + nM;                       // [B,T,C]

  f32_to_bf16_kernel<<<(int)(nM / 4 / 256), 256, 0, stream>>>(x, xb, (int)(nM / 4));
  transpose_bf16_kernel<<<dim3(3 * C / 32, C / 32), 256, 0, stream>>>(W_attn, wat, C, 3 * C);
  transpose_bf16_kernel<<<dim3(C / 32, C / 32), 256, 0, stream>>>(W_proj, wpt, C, C);
  gemm_bt<1><<<dim3(3 * C / 128, Bsz * T / 128), 256, 0, stream>>>(
      xb, wat, nullptr, qp, kp, vp, Bsz * T, 3 * C, C);
  rope_bf16<<<(Bsz * T) / 8, 256, 0, stream>>>(qp, kp, indices);
  flash_attn_mfma<<<dim3(16, H, Bsz), 256, 0, stream>>>(qp, kp, vp, indices, yb);
  gemm_bt<0><<<dim3(C / 128, Bsz * T / 128), 256, 0, stream>>>(
      yb, wpt, out, nullptr, nullptr, nullptr, Bsz * T, C, C);
}

// Round 5
// 304.463 us; speedup vs baseline: 1.1366x; 1.0281x over previous
//
#include <hip/hip_runtime.h>
#include <math.h>

namespace {
constexpr int Bsz = 4;
constexpr int T   = 2048;
constexpr int C   = 1024;
constexpr int H   = 16;
constexpr int HD  = 64;

typedef short bf16x8 __attribute__((ext_vector_type(8)));
typedef float f32x4  __attribute__((ext_vector_type(4)));
typedef unsigned int u32x4 __attribute__((ext_vector_type(4)));

#if defined(__has_builtin)
#if __has_builtin(__builtin_amdgcn_global_load_lds)
#define HAVE_GLL 1
typedef __attribute__((address_space(3))) unsigned int lds_u32_t;
typedef __attribute__((address_space(1))) unsigned int g_u32_t;
#define GLL16(gp, lp)                                                        \
  __builtin_amdgcn_global_load_lds((const g_u32_t*)(gp), (lds_u32_t*)(lp),   \
                                   16, 0, 0)
#endif
#endif

__device__ __forceinline__ unsigned short f2bf(float f) {
  unsigned int u = __builtin_bit_cast(unsigned int, f);
  u += 0x7FFFu + ((u >> 16) & 1u);
  return (unsigned short)(u >> 16);
}
__device__ __forceinline__ float bf2f(unsigned short s) {
  unsigned int u = ((unsigned int)s) << 16;
  return __builtin_bit_cast(float, u);
}
// Packed f32->bf16 (RNE), low16 = a, high16 = b. One VOP3 instr vs 3 ops.
__device__ __forceinline__ unsigned int cvtpk_bf16(float a, float b) {
  unsigned int r;
  asm("v_cvt_pk_bf16_f32 %0, %1, %2" : "=v"(r) : "v"(a), "v"(b));
  return r;
}

// ---------------- fp32 -> bf16 (same layout) ----------------
__global__ __launch_bounds__(256) void f32_to_bf16_kernel(
    const float* __restrict__ in, unsigned short* __restrict__ out, int n4) {
  int i = blockIdx.x * 256 + threadIdx.x;
  if (i < n4) {
    float4 v = ((const float4*)in)[i];
    ushort4 o;
    o.x = f2bf(v.x); o.y = f2bf(v.y); o.z = f2bf(v.z); o.w = f2bf(v.w);
    ((ushort4*)out)[i] = o;
  }
}

// ---------------- W [K,N] fp32 -> Wt [N,K] bf16 ----------------
__global__ __launch_bounds__(256) void transpose_bf16_kernel(
    const float* __restrict__ W, unsigned short* __restrict__ Wt, int K, int N) {
  __shared__ float tile[32][33];
  const int n0 = blockIdx.x * 32, k0 = blockIdx.y * 32;
  const int r = threadIdx.x >> 3, c4 = threadIdx.x & 7;
  float4 v = *(const float4*)(W + (size_t)(k0 + r) * N + n0 + c4 * 4);
  tile[r][c4 * 4 + 0] = v.x;
  tile[r][c4 * 4 + 1] = v.y;
  tile[r][c4 * 4 + 2] = v.z;
  tile[r][c4 * 4 + 3] = v.w;
  __syncthreads();
  ushort4 o;
  o.x = f2bf(tile[c4 * 4 + 0][r]);
  o.y = f2bf(tile[c4 * 4 + 1][r]);
  o.z = f2bf(tile[c4 * 4 + 2][r]);
  o.w = f2bf(tile[c4 * 4 + 3][r]);
  *(ushort4*)(Wt + (size_t)(n0 + r) * K + k0 + c4 * 4) = o;
}

// ---------------- bf16 MFMA GEMM: C[M,N] = A[M,K] @ Bt[N,K]^T ----------------
template <int MODE>
__global__ __launch_bounds__(256) void gemm_bt(
    const unsigned short* __restrict__ A, const unsigned short* __restrict__ Bt,
    float* __restrict__ Cout, unsigned short* __restrict__ qp,
    unsigned short* __restrict__ kp, unsigned short* __restrict__ vp,
    int M, int N, int K) {
  __shared__ __align__(16) unsigned short As[128 * 32];
  __shared__ __align__(16) unsigned short Bs[128 * 32];
  const int tid = threadIdx.x;
  const int lane = tid & 63, w = tid >> 6;
  const int wr = w & 1, wc = w >> 1;
  const int l15 = lane & 15, quad = lane >> 4;
  const int m0 = blockIdx.y * 128, n0 = blockIdx.x * 128;

  const int srow = lane >> 2;
  const int schunk = (lane & 3) * 8;
  const unsigned short* gA = A + (size_t)(m0 + w * 32 + srow) * K + schunk;
  const unsigned short* gB = Bt + (size_t)(n0 + w * 32 + srow) * K + schunk;
  unsigned short* lA0 = &As[(w * 32) * 32 + lane * 8];
  unsigned short* lA1 = &As[(w * 32 + 16) * 32 + lane * 8];
  unsigned short* lB0 = &Bs[(w * 32) * 32 + lane * 8];
  unsigned short* lB1 = &Bs[(w * 32 + 16) * 32 + lane * 8];

  f32x4 acc[4][4] = {};

  for (int k0 = 0; k0 < K; k0 += 32) {
    __syncthreads();
#ifdef HAVE_GLL
    GLL16(gA + k0, lA0);
    GLL16(gA + (size_t)16 * K + k0, lA1);
    GLL16(gB + k0, lB0);
    GLL16(gB + (size_t)16 * K + k0, lB1);
#else
    *(uint4*)lA0 = *(const uint4*)(gA + k0);
    *(uint4*)lA1 = *(const uint4*)(gA + (size_t)16 * K + k0);
    *(uint4*)lB0 = *(const uint4*)(gB + k0);
    *(uint4*)lB1 = *(const uint4*)(gB + (size_t)16 * K + k0);
#endif
    __syncthreads();

    bf16x8 af[4], bfr[4];
#pragma unroll
    for (int mf = 0; mf < 4; ++mf)
      af[mf] = *(const bf16x8*)&As[(wr * 64 + mf * 16 + l15) * 32 + quad * 8];
#pragma unroll
    for (int nf = 0; nf < 4; ++nf)
      bfr[nf] = *(const bf16x8*)&Bs[(wc * 64 + nf * 16 + l15) * 32 + quad * 8];
#pragma unroll
    for (int mf = 0; mf < 4; ++mf)
#pragma unroll
      for (int nf = 0; nf < 4; ++nf)
        acc[mf][nf] = __builtin_amdgcn_mfma_f32_16x16x32_bf16(
            af[mf], bfr[nf], acc[mf][nf], 0, 0, 0);
  }

#pragma unroll
  for (int mf = 0; mf < 4; ++mf) {
    const int row0 = m0 + wr * 64 + mf * 16 + quad * 4;
#pragma unroll
    for (int nf = 0; nf < 4; ++nf) {
      if (MODE == 0) {
#pragma unroll
        for (int r = 0; r < 4; ++r) {
          const int col = n0 + wc * 64 + nf * 16 + l15;
          Cout[(size_t)(row0 + r) * N + col] = acc[mf][nf][r];
        }
      } else {
        const int col = n0 + wc * 64 + nf * 16 + l15;
        const int which = col >> 10;
        const int rem = col & (C - 1);
        const int h = rem >> 6, hd = rem & 63;
        const int b = row0 >> 11, t0 = row0 & (T - 1);
        if (which == 2) {
          ushort4 pv;
          pv.x = f2bf(acc[mf][nf][0]);
          pv.y = f2bf(acc[mf][nf][1]);
          pv.z = f2bf(acc[mf][nf][2]);
          pv.w = f2bf(acc[mf][nf][3]);
          *(ushort4*)(vp + (((size_t)(b * H + h)) * HD + hd) * T + t0) = pv;
        } else {
          unsigned short* dst = which == 0 ? qp : kp;
#pragma unroll
          for (int r = 0; r < 4; ++r)
            dst[(((size_t)(b * H + h)) * T + t0 + r) * HD + hd] =
                f2bf(acc[mf][nf][r]);
        }
      }
    }
  }
}

// ---------------- RoPE in place on bf16 q,k [B,H,T,HD] ----------------
// One 32-lane group owns one (b,t): trig computed ONCE and reused across all
// 16 heads. q additionally pre-scaled by 0.125*log2(e).
__global__ __launch_bounds__(256) void rope_bf16(unsigned short* __restrict__ q,
                                                 unsigned short* __restrict__ k,
                                                 const int* __restrict__ idx) {
  const int g = blockIdx.x * 8 + (threadIdx.x >> 5);  // (b,t) flat index
  const int lane = threadIdx.x & 31;
  const int b = g >> 11, t = g & (T - 1);
  const int pos = idx[b * T + t];
  const float inv = exp2f((float)lane * -0.41524101186f);
  float sn, cs;
  sincosf((float)pos * inv, &sn, &cs);
  const float SC = 0.18033688f;  // 0.125 * log2(e)
  const float snq = sn * SC, csq = cs * SC;
  const size_t base0 = ((size_t)b * H * T + t) * HD + lane;
#pragma unroll 4
  for (int h = 0; h < H; ++h) {
    const size_t base = base0 + (size_t)h * T * HD;
    float x1 = bf2f(q[base]), x2 = bf2f(q[base + 32]);
    q[base]      = f2bf(x1 * csq - x2 * snq);
    q[base + 32] = f2bf(x1 * snq + x2 * csq);
    x1 = bf2f(k[base]);
    x2 = bf2f(k[base + 32]);
    k[base]      = f2bf(x1 * cs - x2 * sn);
    k[base + 32] = f2bf(x1 * sn + x2 * cs);
  }
}

// ---------------- MFMA flash attention ----------------
// Mirror-pair balance: block bx handles q-tiles {bx, 31-bx}; 4 waves own 16
// q-rows each; K/V double-buffered in LDS, one barrier per k-iteration.
//  * P never touches LDS. MFMA sums over K, so the PV contraction uses a
//    permuted K-order chosen so each lane's B-fragment is exactly its own
//    cvt_pk'd QK^T outputs: slot(key) with g=key>>4, qd=(key&15)>>2, i=key&3:
//    slot = 32*(g>>1) + qd*8 + 4*(g&1) + i.  V staged into LDS in slot order.
//    (Internal MFMA lane->k layout cancels: both operands use the same map.)
//  * Cross-quad reductions via __shfl_xor(16/32) — the inline-asm
//    v_permlane*_swap path (rounds 3/4) silently corrupts data: gfx950 has a
//    VALU->permlane hazard wait-state the compiler cannot insert inside an
//    asm blob. DO NOT reintroduce without the hazard-safe builtin + A/B.
//  * l kept quad-local per lane (lq); row sum moved after PV (off the
//    critical path); single cross-quad reduce at epilogue.
//  * mask predicate precomputed as a ballot bitmask (bit 2j = tile j).
__global__ __launch_bounds__(256) void flash_attn_mfma(
    const unsigned short* __restrict__ q, const unsigned short* __restrict__ k,
    const unsigned short* __restrict__ vt, const int* __restrict__ idx,
    unsigned short* __restrict__ y) {
  __shared__ __align__(16) unsigned short Ks[2][64 * 64];   // [buf][key][d] swz
  __shared__ __align__(16) unsigned short Vts[2][64 * 64];  // [buf][d][slot] swz

  const int tid = threadIdx.x;
  const int lane = tid & 63, w = tid >> 6;
  const int l15 = lane & 15, quad = lane >> 4;

  // XCD-aware bijective remap: all 16 q-blocks of one (b,h) on one XCD.
  const int flat = (blockIdx.z * H + blockIdx.y) * 16 + blockIdx.x;
  const int slot_ = flat >> 3;
  const int bh_i = (flat & 7) * 8 + (slot_ >> 4);  // 0..63 = b*H+h
  const int bx = slot_ & 15;
  const int h = bh_i & (H - 1), b = bh_i >> 4;

  const size_t bh = (size_t)bh_i;
  const unsigned short* qg = q + bh * T * HD;
  const unsigned short* kg = k + bh * T * HD;
  const unsigned short* vg = vt + bh * HD * T;
  const int* idxb = idx + b * T;

  // per-64-key-tile idx maxima in registers: lane i maxes idx[i*32..i*32+32);
  // after xor-1 combine, lanes {2j,2j+1} hold the max of tile j.
  int km;
  {
    const int4* p4 = (const int4*)(idxb + (lane << 5));
    int4 v0 = p4[0];
    int m = max(max(v0.x, v0.y), max(v0.z, v0.w));
#pragma unroll
    for (int j = 1; j < 8; ++j) {
      int4 v = p4[j];
      m = max(m, max(max(v.x, v.y), max(v.z, v.w)));
    }
    km = max(m, __shfl_xor(m, 1));
  }

  // staging coords: 64 rows x 8 chunks(16B) = 512 -> 2 per thread
  const int r1 = tid >> 3, c1 = tid & 7;
  const int r2 = r1 + 32;
  const int xr1 = (r1 & 7) << 3;  // r2&7 == r1&7
  // K (unpermuted) swizzled offsets
  const int swS1 = r1 * 64 + ((c1 * 8) ^ xr1);
  const int swS2 = r2 * 64 + ((c1 * 8) ^ xr1);
  // V slot-permuted base for this thread's 8-key chunk
  const int vbase = 32 * (c1 >> 2) + 16 * (c1 & 1) + 4 * ((c1 >> 1) & 1);
  const int vo1a = r1 * 64 + ((vbase + 0) ^ xr1);
  const int vo1b = r1 * 64 + ((vbase + 8) ^ xr1);
  const int vo2a = r2 * 64 + ((vbase + 0) ^ xr1);
  const int vo2b = r2 * 64 + ((vbase + 8) ^ xr1);
  // read-side XOR term (rows read are nf*16+l15 -> low3 = l15&7)
  const int rx = (l15 & 7) << 3;

  for (int ti = 0; ti < 2; ++ti) {
    const int qt = (ti == 0) ? bx : 31 - bx;
    const int qrow = qt * 64 + w * 16 + l15;  // this lane's q row

    const bf16x8 bq0 = *(const bf16x8*)(qg + (size_t)qrow * HD + quad * 8);
    const bf16x8 bq1 = *(const bf16x8*)(qg + (size_t)qrow * HD + 32 + quad * 8);
    const int pq = idxb[qrow];
    // wave-wide min of q positions (pq depends only on l15)
    int mq = pq;
    mq = min(mq, __shfl_xor(mq, 1));
    mq = min(mq, __shfl_xor(mq, 2));
    mq = min(mq, __shfl_xor(mq, 4));
    mq = min(mq, __shfl_xor(mq, 8));
    // mask bitmap: bit 2j set if tile j needs elementwise masking
    const unsigned long long bal = __ballot(km > mq);

    float m_run = -1e38f, lq = 0.0f;
    f32x4 Oa[4] = {};

    // prologue: stage kt=0 into buf 0 (V in slot order)
    {
      uint4 ka = *(const uint4*)(kg + (size_t)r1 * HD + c1 * 8);
      uint4 kb = *(const uint4*)(kg + (size_t)r2 * HD + c1 * 8);
      uint4 va = *(const uint4*)(vg + (size_t)r1 * T + c1 * 8);
      uint4 vb = *(const uint4*)(vg + (size_t)r2 * T + c1 * 8);
      __syncthreads();  // all waves done with previous tile's buffers
      *(uint4*)&Ks[0][swS1] = ka;
      *(uint4*)&Ks[0][swS2] = kb;
      *(uint2*)&Vts[0][vo1a] = make_uint2(va.x, va.y);
      *(uint2*)&Vts[0][vo1b] = make_uint2(va.z, va.w);
      *(uint2*)&Vts[0][vo2a] = make_uint2(vb.x, vb.y);
      *(uint2*)&Vts[0][vo2b] = make_uint2(vb.z, vb.w);
    }

    for (int kt = 0; kt <= qt; ++kt) {
      const int cur = kt & 1;
      const int k0 = kt * 64;
      __syncthreads();  // stage(kt) visible; buf[cur^1] free for restaging

      // issue global loads for kt+1 now; consumed at iteration end
      uint4 nka, nkb, nva, nvb;
      if (kt < qt) {
        const int kn = k0 + 64;
        nka = *(const uint4*)(kg + (size_t)(kn + r1) * HD + c1 * 8);
        nkb = *(const uint4*)(kg + (size_t)(kn + r2) * HD + c1 * 8);
        nva = *(const uint4*)(vg + (size_t)r1 * T + kn + c1 * 8);
        nvb = *(const uint4*)(vg + (size_t)r2 * T + kn + c1 * 8);
      }

      // S^T = K·Q^T : lane = qrow; tile nf reg r = key nf*16+quad*4+r
      f32x4 Sa[4];
      __builtin_amdgcn_s_setprio(1);
#pragma unroll
      for (int nf = 0; nf < 4; ++nf) {
        const int row = (nf * 16 + l15) * 64;
        bf16x8 ak0 = *(const bf16x8*)&Ks[cur][row + ((quad * 8) ^ rx)];
        bf16x8 ak1 = *(const bf16x8*)&Ks[cur][row + ((32 + quad * 8) ^ rx)];
        f32x4 s = {};
        s = __builtin_amdgcn_mfma_f32_16x16x32_bf16(ak0, bq0, s, 0, 0, 0);
        s = __builtin_amdgcn_mfma_f32_16x16x32_bf16(ak1, bq1, s, 0, 0, 0);
        Sa[nf] = s;
      }
      __builtin_amdgcn_s_setprio(0);

      // causal mask only when this tile can exceed some q position (uniform)
      if ((bal >> (kt + kt)) & 1ull) {
#pragma unroll
        for (int nf = 0; nf < 4; ++nf) {
          const int4 pk4 = *(const int4*)(idxb + k0 + nf * 16 + quad * 4);
          if (pk4.x > pq) Sa[nf][0] = -3e38f;
          if (pk4.y > pq) Sa[nf][1] = -3e38f;
          if (pk4.z > pq) Sa[nf][2] = -3e38f;
          if (pk4.w > pq) Sa[nf][3] = -3e38f;
        }
      }

      // row max: 16 local (max3-fused) + cross-quad via shfl (proven path)
      float mx = fmaxf(
          fmaxf(fmaxf(fmaxf(Sa[0][0], Sa[0][1]), Sa[0][2]),
                fmaxf(fmaxf(Sa[0][3], Sa[1][0]), Sa[1][1])),
          fmaxf(fmaxf(fmaxf(Sa[1][2], Sa[1][3]), Sa[2][0]),
                fmaxf(fmaxf(Sa[2][1], Sa[2][2]), Sa[2][3])));
      mx = fmaxf(mx, fmaxf(fmaxf(Sa[3][0], Sa[3][1]), fmaxf(Sa[3][2], Sa[3][3])));
      mx = fmaxf(mx, __shfl_xor(mx, 16));
      mx = fmaxf(mx, __shfl_xor(mx, 32));

      // defer-max: rescale only when some row grew past m_run+8
      if (!__all(mx <= m_run + 8.0f)) {
        const float mn = fmaxf(m_run, mx);
        const float alpha = exp2f(m_run - mn);
        m_run = mn;
        lq *= alpha;
#pragma unroll
        for (int nfd = 0; nfd < 4; ++nfd)
#pragma unroll
          for (int r = 0; r < 4; ++r) Oa[nfd][r] *= alpha;
      }

      // P = exp2(S - m_run), packed lane-locally into the PV B-fragments
      // (K-slot permutation makes these exactly this lane's values).
      u32x4 w0, w1;
#pragma unroll
      for (int nf = 0; nf < 4; ++nf) {
        float p0 = exp2f(Sa[nf][0] - m_run);
        float p1 = exp2f(Sa[nf][1] - m_run);
        float p2 = exp2f(Sa[nf][2] - m_run);
        float p3 = exp2f(Sa[nf][3] - m_run);
        Sa[nf][0] = p0; Sa[nf][1] = p1; Sa[nf][2] = p2; Sa[nf][3] = p3;
        if (nf < 2) {
          w0[nf * 2 + 0] = cvtpk_bf16(p0, p1);
          w0[nf * 2 + 1] = cvtpk_bf16(p2, p3);
        } else {
          w1[(nf - 2) * 2 + 0] = cvtpk_bf16(p0, p1);
          w1[(nf - 2) * 2 + 1] = cvtpk_bf16(p2, p3);
        }
      }
      const bf16x8 bp0 = __builtin_bit_cast(bf16x8, w0);
      const bf16x8 bp1 = __builtin_bit_cast(bf16x8, w1);

      // O^T += V^T · P^T (V already in slot order)
      __builtin_amdgcn_s_setprio(1);
#pragma unroll
      for (int nfd = 0; nfd < 4; ++nfd) {
        const int vrow = (nfd * 16 + l15) * 64;
        bf16x8 av0 = *(const bf16x8*)&Vts[cur][vrow + ((quad * 8) ^ rx)];
        bf16x8 av1 = *(const bf16x8*)&Vts[cur][vrow + ((32 + quad * 8) ^ rx)];
        Oa[nfd] = __builtin_amdgcn_mfma_f32_16x16x32_bf16(av0, bp0, Oa[nfd], 0, 0, 0);
        Oa[nfd] = __builtin_amdgcn_mfma_f32_16x16x32_bf16(av1, bp1, Oa[nfd], 0, 0, 0);
      }
      __builtin_amdgcn_s_setprio(0);

      // quad-local l accumulation (off the critical path, after PV)
      lq += ((Sa[0][0] + Sa[0][1]) + (Sa[0][2] + Sa[0][3])) +
            ((Sa[1][0] + Sa[1][1]) + (Sa[1][2] + Sa[1][3])) +
            ((Sa[2][0] + Sa[2][1]) + (Sa[2][2] + Sa[2][3])) +
            ((Sa[3][0] + Sa[3][1]) + (Sa[3][2] + Sa[3][3]));

      // write next tile into the spare buffer (waits its loads via dep)
      if (kt < qt) {
        const int nxt = cur ^ 1;
        *(uint4*)&Ks[nxt][swS1] = nka;
        *(uint4*)&Ks[nxt][swS2] = nkb;
        *(uint2*)&Vts[nxt][vo1a] = make_uint2(nva.x, nva.y);
        *(uint2*)&Vts[nxt][vo1b] = make_uint2(nva.z, nva.w);
        *(uint2*)&Vts[nxt][vo2a] = make_uint2(nvb.x, nvb.y);
        *(uint2*)&Vts[nxt][vo2b] = make_uint2(nvb.z, nvb.w);
      }
    }

    // epilogue: combine quad-local l via shfl, then store
    float lsum = lq;
    lsum += __shfl_xor(lsum, 16);
    lsum += __shfl_xor(lsum, 32);
    const float rl = 1.0f / lsum;
    const size_t base = ((size_t)b * T + qrow) * (size_t)C + h * HD;
#pragma unroll
    for (int nfd = 0; nfd < 4; ++nfd) {
      ushort4 o;
      o.x = f2bf(Oa[nfd][0] * rl);
      o.y = f2bf(Oa[nfd][1] * rl);
      o.z = f2bf(Oa[nfd][2] * rl);
      o.w = f2bf(Oa[nfd][3] * rl);
      *(ushort4*)(y + base + nfd * 16 + quad * 4) = o;
    }
  }
}

}  // namespace

extern "C" void kernel_launch(void* const* d_in, const int* in_sizes, int n_in,
                              void* d_out, int out_size, void* d_ws,
                              size_t ws_size, hipStream_t stream) {
  const float* x      = (const float*)d_in[0];
  const float* W_attn = (const float*)d_in[1];
  const float* W_proj = (const float*)d_in[2];
  const int* indices  = (const int*)d_in[3];
  float* out = (float*)d_out;

  const size_t nM = (size_t)Bsz * T * C;
  unsigned short* xb  = (unsigned short*)d_ws;
  unsigned short* wat = xb + nM;
  unsigned short* wpt = wat + (size_t)3 * C * C;
  unsigned short* qp  = wpt + (size_t)C * C;           // [B,H,T,HD]
  unsigned short* kp  = qp + nM;                       // [B,H,T,HD]
  unsigned short* vp  = kp + nM;                       // [B,H,HD,T]
  unsigned short* yb  = vp + nM;                       // [B,T,C]

  f32_to_bf16_kernel<<<(int)(nM / 4 / 256), 256, 0, stream>>>(x, xb, (int)(nM / 4));
  transpose_bf16_kernel<<<dim3(3 * C / 32, C / 32), 256, 0, stream>>>(W_attn, wat, C, 3 * C);
  transpose_bf16_kernel<<<dim3(C / 32, C / 32), 256, 0, stream>>>(W_proj, wpt, C, C);
  gemm_bt<1><<<dim3(3 * C / 128, Bsz * T / 128), 256, 0, stream>>>(
      xb, wat, nullptr, qp, kp, vp, Bsz * T, 3 * C, C);
  rope_bf16<<<(Bsz * T) / 8, 256, 0, stream>>>(qp, kp, indices);
  flash_attn_mfma<<<dim3(16, H, Bsz), 256, 0, stream>>>(qp, kp, vp, indices, yb);
  gemm_bt<0><<<dim3(C / 128, Bsz * T / 128), 256, 0, stream>>>(
      yb, wpt, out, nullptr, nullptr, nullptr, Bsz * T, C, C);
}

// Round 6
// 299.815 us; speedup vs baseline: 1.1542x; 1.0155x over previous
//
#include <hip/hip_runtime.h>
#include <math.h>

namespace {
constexpr int Bsz = 4;
constexpr int T   = 2048;
constexpr int C   = 1024;
constexpr int H   = 16;
constexpr int HD  = 64;

typedef short bf16x8 __attribute__((ext_vector_type(8)));
typedef float f32x4  __attribute__((ext_vector_type(4)));
typedef unsigned int u32x4 __attribute__((ext_vector_type(4)));

#if defined(__has_builtin)
#if __has_builtin(__builtin_amdgcn_global_load_lds)
#define HAVE_GLL 1
typedef __attribute__((address_space(3))) unsigned int lds_u32_t;
typedef __attribute__((address_space(1))) unsigned int g_u32_t;
#define GLL16(gp, lp)                                                        \
  __builtin_amdgcn_global_load_lds((const g_u32_t*)(gp), (lds_u32_t*)(lp),   \
                                   16, 0, 0)
#endif
#endif

__device__ __forceinline__ unsigned short f2bf(float f) {
  unsigned int u = __builtin_bit_cast(unsigned int, f);
  u += 0x7FFFu + ((u >> 16) & 1u);
  return (unsigned short)(u >> 16);
}
__device__ __forceinline__ float bf2f(unsigned short s) {
  unsigned int u = ((unsigned int)s) << 16;
  return __builtin_bit_cast(float, u);
}
// Packed f32->bf16 (RNE), low16 = a, high16 = b. One VOP3 instr vs 3 ops.
__device__ __forceinline__ unsigned int cvtpk_bf16(float a, float b) {
  unsigned int r;
  asm("v_cvt_pk_bf16_f32 %0, %1, %2" : "=v"(r) : "v"(a), "v"(b));
  return r;
}

// ---------------- fp32 -> bf16 (same layout) ----------------
__global__ __launch_bounds__(256) void f32_to_bf16_kernel(
    const float* __restrict__ in, unsigned short* __restrict__ out, int n4) {
  int i = blockIdx.x * 256 + threadIdx.x;
  if (i < n4) {
    float4 v = ((const float4*)in)[i];
    ushort4 o;
    o.x = f2bf(v.x); o.y = f2bf(v.y); o.z = f2bf(v.z); o.w = f2bf(v.w);
    ((ushort4*)out)[i] = o;
  }
}

// ---------------- W [K,N] fp32 -> Wt [N,K] bf16 ----------------
__global__ __launch_bounds__(256) void transpose_bf16_kernel(
    const float* __restrict__ W, unsigned short* __restrict__ Wt, int K, int N) {
  __shared__ float tile[32][33];
  const int n0 = blockIdx.x * 32, k0 = blockIdx.y * 32;
  const int r = threadIdx.x >> 3, c4 = threadIdx.x & 7;
  float4 v = *(const float4*)(W + (size_t)(k0 + r) * N + n0 + c4 * 4);
  tile[r][c4 * 4 + 0] = v.x;
  tile[r][c4 * 4 + 1] = v.y;
  tile[r][c4 * 4 + 2] = v.z;
  tile[r][c4 * 4 + 3] = v.w;
  __syncthreads();
  ushort4 o;
  o.x = f2bf(tile[c4 * 4 + 0][r]);
  o.y = f2bf(tile[c4 * 4 + 1][r]);
  o.z = f2bf(tile[c4 * 4 + 2][r]);
  o.w = f2bf(tile[c4 * 4 + 3][r]);
  *(ushort4*)(Wt + (size_t)(n0 + r) * K + k0 + c4 * 4) = o;
}

// ---------------- bf16 MFMA GEMM: C[M,N] = A[M,K] @ Bt[N,K]^T ----------------
// MODE==1 (qkv): RoPE fused into the epilogue. A wave's acc holds BOTH rope
// halves of each (t,d) pair: q/k col hd = nf*16+l15, so (hd, hd+32) are acc
// tiles (nf, nf+2) at the same (mf,r,l15). Rope applied in f32 on the
// accumulator (more accurate than the old bf16 read-modify-write pass);
// softmax scale 0.125*log2(e) folded into q here.
template <int MODE>
__global__ __launch_bounds__(256) void gemm_bt(
    const unsigned short* __restrict__ A, const unsigned short* __restrict__ Bt,
    float* __restrict__ Cout, unsigned short* __restrict__ qp,
    unsigned short* __restrict__ kp, unsigned short* __restrict__ vp,
    const int* __restrict__ idx, int M, int N, int K) {
  __shared__ __align__(16) unsigned short As[128 * 32];
  __shared__ __align__(16) unsigned short Bs[128 * 32];
  const int tid = threadIdx.x;
  const int lane = tid & 63, w = tid >> 6;
  const int wr = w & 1, wc = w >> 1;
  const int l15 = lane & 15, quad = lane >> 4;
  const int m0 = blockIdx.y * 128, n0 = blockIdx.x * 128;

  const int srow = lane >> 2;
  const int schunk = (lane & 3) * 8;
  const unsigned short* gA = A + (size_t)(m0 + w * 32 + srow) * K + schunk;
  const unsigned short* gB = Bt + (size_t)(n0 + w * 32 + srow) * K + schunk;
  unsigned short* lA0 = &As[(w * 32) * 32 + lane * 8];
  unsigned short* lA1 = &As[(w * 32 + 16) * 32 + lane * 8];
  unsigned short* lB0 = &Bs[(w * 32) * 32 + lane * 8];
  unsigned short* lB1 = &Bs[(w * 32 + 16) * 32 + lane * 8];

  f32x4 acc[4][4] = {};

  for (int k0 = 0; k0 < K; k0 += 32) {
    __syncthreads();
#ifdef HAVE_GLL
    GLL16(gA + k0, lA0);
    GLL16(gA + (size_t)16 * K + k0, lA1);
    GLL16(gB + k0, lB0);
    GLL16(gB + (size_t)16 * K + k0, lB1);
#else
    *(uint4*)lA0 = *(const uint4*)(gA + k0);
    *(uint4*)lA1 = *(const uint4*)(gA + (size_t)16 * K + k0);
    *(uint4*)lB0 = *(const uint4*)(gB + k0);
    *(uint4*)lB1 = *(const uint4*)(gB + (size_t)16 * K + k0);
#endif
    __syncthreads();

    bf16x8 af[4], bfr[4];
#pragma unroll
    for (int mf = 0; mf < 4; ++mf)
      af[mf] = *(const bf16x8*)&As[(wr * 64 + mf * 16 + l15) * 32 + quad * 8];
#pragma unroll
    for (int nf = 0; nf < 4; ++nf)
      bfr[nf] = *(const bf16x8*)&Bs[(wc * 64 + nf * 16 + l15) * 32 + quad * 8];
#pragma unroll
    for (int mf = 0; mf < 4; ++mf)
#pragma unroll
      for (int nf = 0; nf < 4; ++nf)
        acc[mf][nf] = __builtin_amdgcn_mfma_f32_16x16x32_bf16(
            af[mf], bfr[nf], acc[mf][nf], 0, 0, 0);
  }

  if (MODE == 0) {
#pragma unroll
    for (int mf = 0; mf < 4; ++mf) {
      const int row0 = m0 + wr * 64 + mf * 16 + quad * 4;
#pragma unroll
      for (int nf = 0; nf < 4; ++nf) {
        const int col = n0 + wc * 64 + nf * 16 + l15;
#pragma unroll
        for (int r = 0; r < 4; ++r)
          Cout[(size_t)(row0 + r) * N + col] = acc[mf][nf][r];
      }
    }
  } else {
    const int colbase = n0 + wc * 64;       // multiple of 64 -> wave-uniform
    const int which = colbase >> 10;        // 0=q 1=k 2=v
    if (which == 2) {
#pragma unroll
      for (int mf = 0; mf < 4; ++mf) {
        const int row0 = m0 + wr * 64 + mf * 16 + quad * 4;
        const int b = row0 >> 11, t0 = row0 & (T - 1);
#pragma unroll
        for (int nf = 0; nf < 4; ++nf) {
          const int rem = (colbase + nf * 16 + l15) & (C - 1);
          const int h = rem >> 6, hd = rem & 63;
          ushort4 pv;
          pv.x = f2bf(acc[mf][nf][0]);
          pv.y = f2bf(acc[mf][nf][1]);
          pv.z = f2bf(acc[mf][nf][2]);
          pv.w = f2bf(acc[mf][nf][3]);
          *(ushort4*)(vp + (((size_t)(b * H + h)) * HD + hd) * T + t0) = pv;
        }
      }
    } else {
      unsigned short* dst = (which == 0) ? qp : kp;
      const float sc = (which == 0) ? 0.18033688f : 1.0f;  // 0.125*log2(e)
      const int h = ((colbase + l15) & (C - 1)) >> 6;      // same h for nf,nf+2
      // inv_freq = 10000^(-d/32) = exp2(-d * log2(10000)/32), d = nf*16+l15
      const float inv0 = exp2f((float)l15 * -0.41524101186f);
      const float inv1 = exp2f((float)(16 + l15) * -0.41524101186f);
#pragma unroll
      for (int mf = 0; mf < 4; ++mf) {
        const int row0 = m0 + wr * 64 + mf * 16 + quad * 4;
        const int b = row0 >> 11, t0 = row0 & (T - 1);
        const int4 pos4 = *(const int4*)(idx + b * T + t0);  // t0 % 4 == 0
        const int pr[4] = {pos4.x, pos4.y, pos4.z, pos4.w};
        const size_t obase = ((size_t)(b * H + h)) * T + t0;
#pragma unroll
        for (int nf = 0; nf < 2; ++nf) {
          const float inv = (nf == 0) ? inv0 : inv1;
          const int d = nf * 16 + l15;
#pragma unroll
          for (int r = 0; r < 4; ++r) {
            float sn, cs;
            sincosf((float)pr[r] * inv, &sn, &cs);
            const float x1 = acc[mf][nf][r], x2 = acc[mf][nf + 2][r];
            dst[(obase + r) * HD + d]      = f2bf((x1 * cs - x2 * sn) * sc);
            dst[(obase + r) * HD + d + 32] = f2bf((x1 * sn + x2 * cs) * sc);
          }
        }
      }
    }
  }
}

// ---------------- MFMA flash attention ----------------
// One 64-row q-tile per block (grid 2048 = 8 blocks/CU avg; LDS 32KB allows
// ~5 resident) -> more waves/SIMD to hide DS latency + barrier drain.
// Longest blocks (qt=31) dispatch FIRST within each XCD group (qt = 31-slot)
// so short blocks backfill the tail. XCD remap keeps all 32 q-blocks of one
// (b,h) on one XCD (K/V L2-resident).
//  * P never touches LDS: PV uses a permuted K-order so each lane's
//    B-fragment is its own cvt_pk'd QK^T outputs; V staged in slot order.
//  * Cross-quad reductions via __shfl_xor(16/32) — the inline-asm
//    v_permlane*_swap path (rounds 3/4) silently corrupts data (hazard or
//    semantics). DO NOT reintroduce without hazard-safe builtin + A/B.
//  * l kept quad-local (lq), summed after PV; single reduce at epilogue.
//  * mask predicate precomputed as a ballot bitmask (bit 2j = tile j).
__global__ __launch_bounds__(256) void flash_attn_mfma(
    const unsigned short* __restrict__ q, const unsigned short* __restrict__ k,
    const unsigned short* __restrict__ vt, const int* __restrict__ idx,
    unsigned short* __restrict__ y) {
  __shared__ __align__(16) unsigned short Ks[2][64 * 64];   // [buf][key][d] swz
  __shared__ __align__(16) unsigned short Vts[2][64 * 64];  // [buf][d][slot] swz

  const int tid = threadIdx.x;
  const int lane = tid & 63, w = tid >> 6;
  const int l15 = lane & 15, quad = lane >> 4;

  // decode: flat in [0,2048); xcd = flat&7; all of one (b,h) on one XCD;
  // qt descending in dispatch order (longest first).
  const int flat = (blockIdx.z * H + blockIdx.y) * 32 + blockIdx.x;
  const int slot = flat >> 3;
  const int bh_i = (flat & 7) * 8 + (slot >> 5);  // 0..63 = b*H+h
  const int qt = 31 - (slot & 31);
  const int h = bh_i & (H - 1), b = bh_i >> 4;

  const size_t bh = (size_t)bh_i;
  const unsigned short* qg = q + bh * T * HD;
  const unsigned short* kg = k + bh * T * HD;
  const unsigned short* vg = vt + bh * HD * T;
  const int* idxb = idx + b * T;

  // per-64-key-tile idx maxima in registers: lane i maxes idx[i*32..i*32+32);
  // after xor-1 combine, lanes {2j,2j+1} hold the max of tile j.
  int km;
  {
    const int4* p4 = (const int4*)(idxb + (lane << 5));
    int4 v0 = p4[0];
    int m = max(max(v0.x, v0.y), max(v0.z, v0.w));
#pragma unroll
    for (int j = 1; j < 8; ++j) {
      int4 v = p4[j];
      m = max(m, max(max(v.x, v.y), max(v.z, v.w)));
    }
    km = max(m, __shfl_xor(m, 1));
  }

  // staging coords: 64 rows x 8 chunks(16B) = 512 -> 2 per thread
  const int r1 = tid >> 3, c1 = tid & 7;
  const int r2 = r1 + 32;
  const int xr1 = (r1 & 7) << 3;  // r2&7 == r1&7
  // K (unpermuted) swizzled offsets
  const int swS1 = r1 * 64 + ((c1 * 8) ^ xr1);
  const int swS2 = r2 * 64 + ((c1 * 8) ^ xr1);
  // V slot-permuted base for this thread's 8-key chunk
  const int vbase = 32 * (c1 >> 2) + 16 * (c1 & 1) + 4 * ((c1 >> 1) & 1);
  const int vo1a = r1 * 64 + ((vbase + 0) ^ xr1);
  const int vo1b = r1 * 64 + ((vbase + 8) ^ xr1);
  const int vo2a = r2 * 64 + ((vbase + 0) ^ xr1);
  const int vo2b = r2 * 64 + ((vbase + 8) ^ xr1);
  // read-side XOR term (rows read are nf*16+l15 -> low3 = l15&7)
  const int rx = (l15 & 7) << 3;

  const int qrow = qt * 64 + w * 16 + l15;  // this lane's q row

  const bf16x8 bq0 = *(const bf16x8*)(qg + (size_t)qrow * HD + quad * 8);
  const bf16x8 bq1 = *(const bf16x8*)(qg + (size_t)qrow * HD + 32 + quad * 8);
  const int pq = idxb[qrow];
  // wave-wide min of q positions (pq depends only on l15)
  int mq = pq;
  mq = min(mq, __shfl_xor(mq, 1));
  mq = min(mq, __shfl_xor(mq, 2));
  mq = min(mq, __shfl_xor(mq, 4));
  mq = min(mq, __shfl_xor(mq, 8));
  // mask bitmap: bit 2j set if tile j needs elementwise masking
  const unsigned long long bal = __ballot(km > mq);

  float m_run = -1e38f, lq = 0.0f;
  f32x4 Oa[4] = {};

  // prologue: stage kt=0 into buf 0 (V in slot order)
  {
    uint4 ka = *(const uint4*)(kg + (size_t)r1 * HD + c1 * 8);
    uint4 kb = *(const uint4*)(kg + (size_t)r2 * HD + c1 * 8);
    uint4 va = *(const uint4*)(vg + (size_t)r1 * T + c1 * 8);
    uint4 vb = *(const uint4*)(vg + (size_t)r2 * T + c1 * 8);
    *(uint4*)&Ks[0][swS1] = ka;
    *(uint4*)&Ks[0][swS2] = kb;
    *(uint2*)&Vts[0][vo1a] = make_uint2(va.x, va.y);
    *(uint2*)&Vts[0][vo1b] = make_uint2(va.z, va.w);
    *(uint2*)&Vts[0][vo2a] = make_uint2(vb.x, vb.y);
    *(uint2*)&Vts[0][vo2b] = make_uint2(vb.z, vb.w);
  }

  for (int kt = 0; kt <= qt; ++kt) {
    const int cur = kt & 1;
    const int k0 = kt * 64;
    __syncthreads();  // stage(kt) visible; buf[cur^1] free for restaging

    // issue global loads for kt+1 now; consumed at iteration end
    uint4 nka, nkb, nva, nvb;
    if (kt < qt) {
      const int kn = k0 + 64;
      nka = *(const uint4*)(kg + (size_t)(kn + r1) * HD + c1 * 8);
      nkb = *(const uint4*)(kg + (size_t)(kn + r2) * HD + c1 * 8);
      nva = *(const uint4*)(vg + (size_t)r1 * T + kn + c1 * 8);
      nvb = *(const uint4*)(vg + (size_t)r2 * T + kn + c1 * 8);
    }

    // S^T = K·Q^T : lane = qrow; tile nf reg r = key nf*16+quad*4+r
    f32x4 Sa[4];
    __builtin_amdgcn_s_setprio(1);
#pragma unroll
    for (int nf = 0; nf < 4; ++nf) {
      const int row = (nf * 16 + l15) * 64;
      bf16x8 ak0 = *(const bf16x8*)&Ks[cur][row + ((quad * 8) ^ rx)];
      bf16x8 ak1 = *(const bf16x8*)&Ks[cur][row + ((32 + quad * 8) ^ rx)];
      f32x4 s = {};
      s = __builtin_amdgcn_mfma_f32_16x16x32_bf16(ak0, bq0, s, 0, 0, 0);
      s = __builtin_amdgcn_mfma_f32_16x16x32_bf16(ak1, bq1, s, 0, 0, 0);
      Sa[nf] = s;
    }
    __builtin_amdgcn_s_setprio(0);

    // causal mask only when this tile can exceed some q position (uniform)
    if ((bal >> (kt + kt)) & 1ull) {
#pragma unroll
      for (int nf = 0; nf < 4; ++nf) {
        const int4 pk4 = *(const int4*)(idxb + k0 + nf * 16 + quad * 4);
        if (pk4.x > pq) Sa[nf][0] = -3e38f;
        if (pk4.y > pq) Sa[nf][1] = -3e38f;
        if (pk4.z > pq) Sa[nf][2] = -3e38f;
        if (pk4.w > pq) Sa[nf][3] = -3e38f;
      }
    }

    // row max: 16 local (max3-fused) + cross-quad via shfl (proven path)
    float mx = fmaxf(
        fmaxf(fmaxf(fmaxf(Sa[0][0], Sa[0][1]), Sa[0][2]),
              fmaxf(fmaxf(Sa[0][3], Sa[1][0]), Sa[1][1])),
        fmaxf(fmaxf(fmaxf(Sa[1][2], Sa[1][3]), Sa[2][0]),
              fmaxf(fmaxf(Sa[2][1], Sa[2][2]), Sa[2][3])));
    mx = fmaxf(mx, fmaxf(fmaxf(Sa[3][0], Sa[3][1]), fmaxf(Sa[3][2], Sa[3][3])));
    mx = fmaxf(mx, __shfl_xor(mx, 16));
    mx = fmaxf(mx, __shfl_xor(mx, 32));

    // defer-max: rescale only when some row grew past m_run+8
    if (!__all(mx <= m_run + 8.0f)) {
      const float mn = fmaxf(m_run, mx);
      const float alpha = exp2f(m_run - mn);
      m_run = mn;
      lq *= alpha;
#pragma unroll
      for (int nfd = 0; nfd < 4; ++nfd)
#pragma unroll
        for (int r = 0; r < 4; ++r) Oa[nfd][r] *= alpha;
    }

    // P = exp2(S - m_run), packed lane-locally into the PV B-fragments
    u32x4 w0, w1;
#pragma unroll
    for (int nf = 0; nf < 4; ++nf) {
      float p0 = exp2f(Sa[nf][0] - m_run);
      float p1 = exp2f(Sa[nf][1] - m_run);
      float p2 = exp2f(Sa[nf][2] - m_run);
      float p3 = exp2f(Sa[nf][3] - m_run);
      Sa[nf][0] = p0; Sa[nf][1] = p1; Sa[nf][2] = p2; Sa[nf][3] = p3;
      if (nf < 2) {
        w0[nf * 2 + 0] = cvtpk_bf16(p0, p1);
        w0[nf * 2 + 1] = cvtpk_bf16(p2, p3);
      } else {
        w1[(nf - 2) * 2 + 0] = cvtpk_bf16(p0, p1);
        w1[(nf - 2) * 2 + 1] = cvtpk_bf16(p2, p3);
      }
    }
    const bf16x8 bp0 = __builtin_bit_cast(bf16x8, w0);
    const bf16x8 bp1 = __builtin_bit_cast(bf16x8, w1);

    // O^T += V^T · P^T (V already in slot order)
    __builtin_amdgcn_s_setprio(1);
#pragma unroll
    for (int nfd = 0; nfd < 4; ++nfd) {
      const int vrow = (nfd * 16 + l15) * 64;
      bf16x8 av0 = *(const bf16x8*)&Vts[cur][vrow + ((quad * 8) ^ rx)];
      bf16x8 av1 = *(const bf16x8*)&Vts[cur][vrow + ((32 + quad * 8) ^ rx)];
      Oa[nfd] = __builtin_amdgcn_mfma_f32_16x16x32_bf16(av0, bp0, Oa[nfd], 0, 0, 0);
      Oa[nfd] = __builtin_amdgcn_mfma_f32_16x16x32_bf16(av1, bp1, Oa[nfd], 0, 0, 0);
    }
    __builtin_amdgcn_s_setprio(0);

    // quad-local l accumulation (off the critical path, after PV)
    lq += ((Sa[0][0] + Sa[0][1]) + (Sa[0][2] + Sa[0][3])) +
          ((Sa[1][0] + Sa[1][1]) + (Sa[1][2] + Sa[1][3])) +
          ((Sa[2][0] + Sa[2][1]) + (Sa[2][2] + Sa[2][3])) +
          ((Sa[3][0] + Sa[3][1]) + (Sa[3][2] + Sa[3][3]));

    // write next tile into the spare buffer (waits its loads via dep)
    if (kt < qt) {
      const int nxt = cur ^ 1;
      *(uint4*)&Ks[nxt][swS1] = nka;
      *(uint4*)&Ks[nxt][swS2] = nkb;
      *(uint2*)&Vts[nxt][vo1a] = make_uint2(nva.x, nva.y);
      *(uint2*)&Vts[nxt][vo1b] = make_uint2(nva.z, nva.w);
      *(uint2*)&Vts[nxt][vo2a] = make_uint2(nvb.x, nvb.y);
      *(uint2*)&Vts[nxt][vo2b] = make_uint2(nvb.z, nvb.w);
    }
  }

  // epilogue: combine quad-local l via shfl, then store
  float lsum = lq;
  lsum += __shfl_xor(lsum, 16);
  lsum += __shfl_xor(lsum, 32);
  const float rl = 1.0f / lsum;
  const size_t base = ((size_t)b * T + qrow) * (size_t)C + h * HD;
#pragma unroll
  for (int nfd = 0; nfd < 4; ++nfd) {
    ushort4 o;
    o.x = f2bf(Oa[nfd][0] * rl);
    o.y = f2bf(Oa[nfd][1] * rl);
    o.z = f2bf(Oa[nfd][2] * rl);
    o.w = f2bf(Oa[nfd][3] * rl);
    *(ushort4*)(y + base + nfd * 16 + quad * 4) = o;
  }
}

}  // namespace

extern "C" void kernel_launch(void* const* d_in, const int* in_sizes, int n_in,
                              void* d_out, int out_size, void* d_ws,
                              size_t ws_size, hipStream_t stream) {
  const float* x      = (const float*)d_in[0];
  const float* W_attn = (const float*)d_in[1];
  const float* W_proj = (const float*)d_in[2];
  const int* indices  = (const int*)d_in[3];
  float* out = (float*)d_out;

  const size_t nM = (size_t)Bsz * T * C;
  unsigned short* xb  = (unsigned short*)d_ws;
  unsigned short* wat = xb + nM;
  unsigned short* wpt = wat + (size_t)3 * C * C;
  unsigned short* qp  = wpt + (size_t)C * C;           // [B,H,T,HD]
  unsigned short* kp  = qp + nM;                       // [B,H,T,HD]
  unsigned short* vp  = kp + nM;                       // [B,H,HD,T]
  unsigned short* yb  = vp + nM;                       // [B,T,C]

  f32_to_bf16_kernel<<<(int)(nM / 4 / 256), 256, 0, stream>>>(x, xb, (int)(nM / 4));
  transpose_bf16_kernel<<<dim3(3 * C / 32, C / 32), 256, 0, stream>>>(W_attn, wat, C, 3 * C);
  transpose_bf16_kernel<<<dim3(C / 32, C / 32), 256, 0, stream>>>(W_proj, wpt, C, C);
  gemm_bt<1><<<dim3(3 * C / 128, Bsz * T / 128), 256, 0, stream>>>(
      xb, wat, nullptr, qp, kp, vp, indices, Bsz * T, 3 * C, C);
  flash_attn_mfma<<<dim3(32, H, Bsz), 256, 0, stream>>>(qp, kp, vp, indices, yb);
  gemm_bt<0><<<dim3(C / 128, Bsz * T / 128), 256, 0, stream>>>(
      yb, wpt, out, nullptr, nullptr, nullptr, nullptr, Bsz * T, C, C);
}